// Round 1
// baseline (770.295 us; speedup 1.0000x reference)
//
#include <hip/hip_runtime.h>
#include <hip/hip_bf16.h>
#include <stdint.h>

#define HEADS 4
#define SLOPE 0.2f

typedef unsigned short u16;
typedef float f32x4 __attribute__((ext_vector_type(4)));
typedef short s16x8 __attribute__((ext_vector_type(8)));

__device__ __forceinline__ u16 f2bf(float f) {
    unsigned int u = __float_as_uint(f);
    u = (u + 0x7fffu + ((u >> 16) & 1u)) >> 16;   // round-to-nearest-even
    return (u16)u;
}
__device__ __forceinline__ float bf2f(u16 v) {
    return __uint_as_float(((unsigned int)v) << 16);
}
__device__ __forceinline__ float fin(float x) {
    return (x == x && fabsf(x) < 1e30f) ? x : 0.f;
}

// ---------------------------------------------------------------- fused prep
// zero(deg) + cast inp -> Xb (flat [N][128]) + transpose W1/W2/W3.
__global__ void prep_kernel(const float* __restrict__ inp, u16* __restrict__ Xb,
                            const float* __restrict__ W1, u16* __restrict__ Wt1,
                            const float* __restrict__ W2, u16* __restrict__ Wt2,
                            const float* __restrict__ W3, u16* __restrict__ Wt3,
                            int* __restrict__ deg, int N) {
    int i = blockIdx.x * blockDim.x + threadIdx.x;
    int castN = N * 128;
    if (i < N) deg[i] = 0;
    i -= N;
    if (i >= 0 && i < castN) {
        Xb[i] = f2bf(fin(inp[i]));
        return;
    }
    i -= castN;
    if (i >= 0 && i < 128 * 256) {          // W1 [128 x 256] -> Wt1 [256 x 128]
        int k = i >> 8, m = i & 255;
        Wt1[m * 128 + k] = f2bf(fin(W1[i]));
        return;
    }
    i -= 128 * 256;
    if (i >= 0 && i < 256 * 256) {
        int k = i >> 8, m = i & 255;
        Wt2[m * 256 + k] = f2bf(fin(W2[i]));
        return;
    }
    i -= 256 * 256;
    if (i >= 0 && i < 256 * 256) {
        int k = i >> 8, m = i & 255;
        Wt3[m * 256 + k] = f2bf(fin(W3[i]));
    }
}

// ---------------------------------------------------------------- CSR build
__global__ void count_kernel(const int* __restrict__ dst, int* __restrict__ deg,
                             int E, int N) {
    int i = blockIdx.x * blockDim.x + threadIdx.x;
    if (i < E + N) {
        int d = (i < E) ? dst[i] : (i - E);   // self-loops appended
        d = ((unsigned)d < (unsigned)N) ? d : 0;
        atomicAdd(&deg[d], 1);
    }
}

// Single-dispatch scan: block b redundantly sums deg[0 .. b*1024), then scans
// its own 1024-element chunk (O(B^2) pre-sum is cheap at B=49).
__global__ __launch_bounds__(256) void scan_kernel(const int* __restrict__ deg,
                                                   int* __restrict__ rowstart,
                                                   int* __restrict__ cursor, int N) {
    __shared__ int wsum[4];
    __shared__ int sm[256];
    int b = blockIdx.x, tid = threadIdx.x;
    int start = b * 1024;
    int pre = 0;
    for (int i = tid; i < start; i += 256) pre += deg[i];
    #pragma unroll
    for (int off = 1; off <= 32; off <<= 1) pre += __shfl_xor(pre, off);
    if ((tid & 63) == 0) wsum[tid >> 6] = pre;
    __syncthreads();
    int block_pre = wsum[0] + wsum[1] + wsum[2] + wsum[3];

    int base = start + tid * 4;
    int v[4]; int s = 0;
    #pragma unroll
    for (int j = 0; j < 4; j++) { int i = base + j; v[j] = (i < N) ? deg[i] : 0; s += v[j]; }
    sm[tid] = s;
    __syncthreads();
    for (int off = 1; off < 256; off <<= 1) {
        int t = (tid >= off) ? sm[tid - off] : 0;
        __syncthreads();
        sm[tid] += t;
        __syncthreads();
    }
    int run = block_pre + sm[tid] - s;
    #pragma unroll
    for (int j = 0; j < 4; j++) {
        int i = base + j;
        if (i < N) { rowstart[i] = run; cursor[i] = run; run += v[j]; }
    }
    if (b == gridDim.x - 1 && tid == 255) rowstart[N] = block_pre + sm[255];
}

__global__ void scatter_kernel(const int* __restrict__ src, const int* __restrict__ dst,
                               int* __restrict__ cursor, int* __restrict__ csr,
                               int E, int N) {
    int i = blockIdx.x * blockDim.x + threadIdx.x;
    if (i < E + N) {
        int s, d;
        if (i < E) { s = src[i]; d = dst[i]; }
        else       { s = i - E; d = i - E; }
        s = ((unsigned)s < (unsigned)N) ? s : 0;
        d = ((unsigned)d < (unsigned)N) ? d : 0;
        int pos = atomicAdd(&cursor[d], 1);
        if ((unsigned)pos < (unsigned)(E + N)) csr[pos] = s;
    }
}

// ---------------------------------------------------------------- GEMM + fused alphas
// Hb[N x 256] = Xb[N x K] @ W; plus as/ad[n][h] = sum_c Hb[n][h*64+c]*att_{src,dst}[h*64+c]
// computed from the accumulators before the bf16 store (saves a full Hb re-read).
__global__ __launch_bounds__(256) void gemm_kernel(
        const u16* __restrict__ X, const u16* __restrict__ Wt,
        u16* __restrict__ Hout, const float* __restrict__ att_src,
        const float* __restrict__ att_dst, float* __restrict__ as_out,
        float* __restrict__ ad_out, int N, int K) {
    int wv = threadIdx.x >> 6, lane = threadIdx.x & 63;
    int quad = lane >> 4, l16 = lane & 15;
    int m0 = (blockIdx.x * 2 + (wv & 1)) * 32;
    int n0 = (wv >> 1) * 128;

    f32x4 acc[2][8];
    #pragma unroll
    for (int r = 0; r < 2; r++)
        #pragma unroll
        for (int c = 0; c < 8; c++) acc[r][c] = (f32x4){0.f, 0.f, 0.f, 0.f};

    for (int k0 = 0; k0 < K; k0 += 32) {
        s16x8 a[2], b[8];
        #pragma unroll
        for (int r = 0; r < 2; r++) {
            int row = m0 + r * 16 + l16;
            row = row < N ? row : N - 1;
            a[r] = *(const s16x8*)(X + (size_t)row * K + k0 + quad * 8);
        }
        #pragma unroll
        for (int c = 0; c < 8; c++) {
            int n = n0 + c * 16 + l16;
            b[c] = *(const s16x8*)(Wt + (size_t)n * K + k0 + quad * 8);
        }
        #pragma unroll
        for (int r = 0; r < 2; r++)
            #pragma unroll
            for (int c = 0; c < 8; c++)
                acc[r][c] = __builtin_amdgcn_mfma_f32_16x16x32_bf16(a[r], b[c], acc[r][c], 0, 0, 0);
    }

    // Epilogue: store bf16 H and accumulate alpha partials.
    // C/D layout: col = n0 + c*16 + l16, row = m0 + r*16 + quad*4 + j.
    int head0 = n0 >> 6;
    float aps[2][4][2], apd[2][4][2];   // [r][j][hh]
    #pragma unroll
    for (int r = 0; r < 2; r++)
        #pragma unroll
        for (int j = 0; j < 4; j++)
            aps[r][j][0] = aps[r][j][1] = apd[r][j][0] = apd[r][j][1] = 0.f;

    #pragma unroll
    for (int r = 0; r < 2; r++) {
        int rowb = m0 + r * 16 + quad * 4;
        #pragma unroll
        for (int c = 0; c < 8; c++) {
            int col = n0 + c * 16 + l16;
            float av = fin(att_src[col]);
            float dv = fin(att_dst[col]);
            int hh = c >> 2;
            #pragma unroll
            for (int j = 0; j < 4; j++) {
                int row = rowb + j;
                float v = acc[r][c][j];
                aps[r][j][hh] += v * av;
                apd[r][j][hh] += v * dv;
                if (row < N) Hout[(size_t)row * 256 + col] = f2bf(v);
            }
        }
    }
    // reduce over the 16 l16 lanes (columns within a head-half)
    #pragma unroll
    for (int off = 1; off <= 8; off <<= 1) {
        #pragma unroll
        for (int r = 0; r < 2; r++)
            #pragma unroll
            for (int j = 0; j < 4; j++) {
                aps[r][j][0] += __shfl_xor(aps[r][j][0], off);
                aps[r][j][1] += __shfl_xor(aps[r][j][1], off);
                apd[r][j][0] += __shfl_xor(apd[r][j][0], off);
                apd[r][j][1] += __shfl_xor(apd[r][j][1], off);
            }
    }
    if (l16 == 0) {
        #pragma unroll
        for (int r = 0; r < 2; r++) {
            int rowb = m0 + r * 16 + quad * 4;
            #pragma unroll
            for (int j = 0; j < 4; j++) {
                int row = rowb + j;
                if (row < N) {
                    #pragma unroll
                    for (int hh = 0; hh < 2; hh++) {
                        as_out[row * 4 + head0 + hh] = aps[r][j][hh];
                        ad_out[row * 4 + head0 + hh] = apd[r][j][hh];
                    }
                }
            }
        }
    }
}

// ---------------------------------------------------------------- edge weights
// One wave per node. lane = es*4 + h (16 edge slots x 4 heads). Computes the
// un-normalized softmax weight once per (edge, head) and 1/sum per (node, head).
// Replaces the per-edge exp/leaky/alpha-gather that the old fused gather redid
// 8x per head inside the 435 MB row-read loop.
__global__ __launch_bounds__(256) void weight_kernel(
        const float* __restrict__ asrc, const float* __restrict__ adst,
        const int* __restrict__ rowstart, const int* __restrict__ csr,
        float* __restrict__ wraw, float* __restrict__ invws, int N, int Etot) {
    int wv = threadIdx.x >> 6, lane = threadIdx.x & 63;
    int n = blockIdx.x * 4 + wv;
    if (n >= N) return;
    int es = lane >> 2, h = lane & 3;
    int i0 = rowstart[n], i1 = rowstart[n + 1];
    i0 = min(max(i0, 0), Etot);
    i1 = min(max(i1, i0), Etot);
    float adh = adst[n * 4 + h];
    float* wh = wraw + (size_t)h * Etot;
    float ws = 0.f;
    for (int i = i0 + es; i < i1; i += 16) {
        int s = __builtin_nontemporal_load(csr + i);
        s = ((unsigned)s < (unsigned)N) ? s : 0;
        float e = asrc[s * 4 + h] + adh;
        e = e > 0.f ? e : SLOPE * e;
        float w = __expf(fminf(e, 80.f));   // max-free softmax (clamp 80), same as before
        ws += w;
        wh[i] = w;
    }
    #pragma unroll
    for (int off = 4; off <= 32; off <<= 1) ws += __shfl_xor(ws, off);
    if (es == 0) invws[n * 4 + h] = (ws > 0.f) ? 1.f / ws : 0.f;
}

// ---------------------------------------------------------------- chunked SpMM gather
// Pure weighted neighbor-sum, channel-chunked so the Hb slice is L2-resident.
// 8 chunks of 32 channels: slice = 50000*32*2B = 3.2 MB < 4 MB XCD L2.
// chunk = blockIdx.x & 7 pins each chunk to one XCD (round-robin block->XCD);
// wrong mapping only costs locality, never correctness.
// Wave = 4 nodes x 4 edge slots x 4 lanes(16B). Per edge exactly one 64B line.
// csr/w streams are non-temporal so they don't evict the slice.
__global__ __launch_bounds__(256) void spmm_kernel(
        const u16* __restrict__ Hb, const float* __restrict__ wraw,
        const float* __restrict__ invws, const int* __restrict__ rowstart,
        const int* __restrict__ csr, const float* __restrict__ bias,
        u16* __restrict__ outb, float* __restrict__ outf, int write_f32,
        int N, int Etot) {
    int chunk = blockIdx.x & 7;
    int nb = blockIdx.x >> 3;
    int wv = threadIdx.x >> 6, lane = threadIdx.x & 63;
    int n = nb * 16 + wv * 4 + (lane >> 4);
    if (n >= N) return;
    int slot = (lane >> 2) & 3, cg = lane & 3;
    int h = chunk >> 1;

    int i0 = rowstart[n], i1 = rowstart[n + 1];
    i0 = min(max(i0, 0), Etot);
    i1 = min(max(i1, i0), Etot);

    const float* wL = wraw + (size_t)h * Etot;
    const u16* Hc = Hb + chunk * 32 + cg * 8;

    float acc[8];
    #pragma unroll
    for (int j = 0; j < 8; j++) acc[j] = 0.f;

    int i = i0 + slot;
    for (; i + 4 < i1; i += 8) {          // x2 unroll: 2 independent lines in flight/slot
        int sA = __builtin_nontemporal_load(csr + i);
        int sB = __builtin_nontemporal_load(csr + i + 4);
        sA = ((unsigned)sA < (unsigned)N) ? sA : 0;
        sB = ((unsigned)sB < (unsigned)N) ? sB : 0;
        float wA = __builtin_nontemporal_load(wL + i);
        float wB = __builtin_nontemporal_load(wL + i + 4);
        s16x8 hvA = *(const s16x8*)(Hc + (size_t)sA * 256);
        s16x8 hvB = *(const s16x8*)(Hc + (size_t)sB * 256);
        #pragma unroll
        for (int j = 0; j < 8; j++)
            acc[j] += wA * bf2f((u16)hvA[j]) + wB * bf2f((u16)hvB[j]);
    }
    if (i < i1) {
        int s = __builtin_nontemporal_load(csr + i);
        s = ((unsigned)s < (unsigned)N) ? s : 0;
        float w = __builtin_nontemporal_load(wL + i);
        s16x8 hv = *(const s16x8*)(Hc + (size_t)s * 256);
        #pragma unroll
        for (int j = 0; j < 8; j++) acc[j] += w * bf2f((u16)hv[j]);
    }

    // reduce across the 4 edge slots (lane bits 2-3)
    #pragma unroll
    for (int j = 0; j < 8; j++) {
        acc[j] += __shfl_xor(acc[j], 4);
        acc[j] += __shfl_xor(acc[j], 8);
    }

    if (slot == 0) {
        float inv = invws[n * 4 + h];
        int ch = chunk * 32 + cg * 8;
        size_t base = (size_t)n * 256 + ch;
        float o[8];
        #pragma unroll
        for (int j = 0; j < 8; j++) {
            float v = acc[j] * inv + fin(bias[ch + j]);
            o[j] = v > 0.f ? v : (__expf(v) - 1.f);   // ELU
        }
        if (write_f32) {
            f32x4 lo = {o[0], o[1], o[2], o[3]}, hi = {o[4], o[5], o[6], o[7]};
            *(f32x4*)(outf + base) = lo;
            *(f32x4*)(outf + base + 4) = hi;
        } else {
            s16x8 ob;
            #pragma unroll
            for (int j = 0; j < 8; j++) ob[j] = (short)f2bf(o[j]);
            *(s16x8*)(outb + base) = ob;
        }
    }
}

// ---------------------------------------------------------------- launch
extern "C" void kernel_launch(void* const* d_in, const int* in_sizes, int n_in,
                              void* d_out, int out_size, void* d_ws, size_t ws_size,
                              hipStream_t stream) {
    const float* inp  = (const float*)d_in[0];
    const int*   ei   = (const int*)d_in[1];
    const float* W1   = (const float*)d_in[2];
    const float* at_s1= (const float*)d_in[3];
    const float* at_d1= (const float*)d_in[4];
    const float* b1   = (const float*)d_in[5];
    const float* W2   = (const float*)d_in[6];
    const float* at_s2= (const float*)d_in[7];
    const float* at_d2= (const float*)d_in[8];
    const float* b2   = (const float*)d_in[9];
    const float* W3   = (const float*)d_in[10];
    const float* at_s3= (const float*)d_in[11];
    const float* at_d3= (const float*)d_in[12];
    const float* b3   = (const float*)d_in[13];

    const int N = in_sizes[0] / 128;   // 50000
    const int E = in_sizes[1] / 2;     // 800000
    const int Etot = E + N;
    const int* esrc = ei;
    const int* edst = ei + E;

    char* p = (char*)d_ws;
    auto alloc = [&](size_t b) -> void* {
        void* q = (void*)p;
        p += (b + 255) & ~(size_t)255;
        return q;
    };
    u16*   Xb       = (u16*)alloc((size_t)N * 256 * 2);
    u16*   Hb       = (u16*)alloc((size_t)N * 256 * 2);
    u16*   Wt1      = (u16*)alloc((size_t)128 * 256 * 2);
    u16*   Wt2      = (u16*)alloc((size_t)256 * 256 * 2);
    u16*   Wt3      = (u16*)alloc((size_t)256 * 256 * 2);
    float* asb      = (float*)alloc((size_t)N * 4 * 4);
    float* adb      = (float*)alloc((size_t)N * 4 * 4);
    int*   deg      = (int*)alloc((size_t)N * 4);
    int*   rowstart = (int*)alloc((size_t)(N + 1) * 4);
    int*   cursor   = (int*)alloc((size_t)N * 4);
    int*   csr      = (int*)alloc((size_t)Etot * 4);
    float* wraw     = (float*)alloc((size_t)4 * Etot * 4);   // [4][Etot] un-normalized weights
    float* invw     = (float*)alloc((size_t)N * 4 * 4);      // [N][4] 1/sum
    float* outf     = (float*)d_out;

    const int SB = (N + 1023) / 1024;
    const int prep_total = N + N * 128 + 128 * 256 + 2 * 256 * 256;

    prep_kernel<<<(prep_total + 255) / 256, 256, 0, stream>>>(
        inp, Xb, W1, Wt1, W2, Wt2, W3, Wt3, deg, N);
    count_kernel<<<(Etot + 255) / 256, 256, 0, stream>>>(edst, deg, E, N);
    scan_kernel<<<SB, 256, 0, stream>>>(deg, rowstart, cursor, N);
    scatter_kernel<<<(Etot + 255) / 256, 256, 0, stream>>>(esrc, edst, cursor, csr, E, N);

    const int gemm_grid = (N + 63) / 64;
    const int wgt_grid  = (N + 3) / 4;
    const int spmm_grid = ((N + 15) / 16) * 8;

    // layer 1 (K=128)
    gemm_kernel<<<gemm_grid, 256, 0, stream>>>(Xb, Wt1, Hb, at_s1, at_d1, asb, adb, N, 128);
    weight_kernel<<<wgt_grid, 256, 0, stream>>>(asb, adb, rowstart, csr, wraw, invw, N, Etot);
    spmm_kernel<<<spmm_grid, 256, 0, stream>>>(Hb, wraw, invw, rowstart, csr, b1,
                                               Xb, outf, 0, N, Etot);
    // layer 2 (K=256)
    gemm_kernel<<<gemm_grid, 256, 0, stream>>>(Xb, Wt2, Hb, at_s2, at_d2, asb, adb, N, 256);
    weight_kernel<<<wgt_grid, 256, 0, stream>>>(asb, adb, rowstart, csr, wraw, invw, N, Etot);
    spmm_kernel<<<spmm_grid, 256, 0, stream>>>(Hb, wraw, invw, rowstart, csr, b2,
                                               Xb, outf, 0, N, Etot);
    // layer 3 (K=256) -> fp32 d_out
    gemm_kernel<<<gemm_grid, 256, 0, stream>>>(Xb, Wt3, Hb, at_s3, at_d3, asb, adb, N, 256);
    weight_kernel<<<wgt_grid, 256, 0, stream>>>(asb, adb, rowstart, csr, wraw, invw, N, Etot);
    spmm_kernel<<<spmm_grid, 256, 0, stream>>>(Hb, wraw, invw, rowstart, csr, b3,
                                               Xb, outf, 1, N, Etot);
}

// Round 2
// 499.167 us; speedup vs baseline: 1.5432x; 1.5432x over previous
//
#include <hip/hip_runtime.h>
#include <hip/hip_bf16.h>
#include <stdint.h>

#define HEADS 4
#define SLOPE 0.2f

typedef unsigned short u16;
typedef float f32x4 __attribute__((ext_vector_type(4)));
typedef short s16x8 __attribute__((ext_vector_type(8)));
typedef unsigned short u16x4 __attribute__((ext_vector_type(4)));

__device__ __forceinline__ u16 f2bf(float f) {
    unsigned int u = __float_as_uint(f);
    u = (u + 0x7fffu + ((u >> 16) & 1u)) >> 16;   // round-to-nearest-even
    return (u16)u;
}
__device__ __forceinline__ float bf2f(u16 v) {
    return __uint_as_float(((unsigned int)v) << 16);
}
__device__ __forceinline__ float fin(float x) {
    return (x == x && fabsf(x) < 1e30f) ? x : 0.f;
}

// ---------------------------------------------------------------- fused prep
// Vectorized cast inp -> Xb (f32x4 -> u16x4), zero(deg), transpose W1/W2/W3.
__global__ void prep_kernel(const float* __restrict__ inp, u16* __restrict__ Xb,
                            const float* __restrict__ W1, u16* __restrict__ Wt1,
                            const float* __restrict__ W2, u16* __restrict__ Wt2,
                            const float* __restrict__ W3, u16* __restrict__ Wt3,
                            int* __restrict__ deg, int N) {
    int i = blockIdx.x * blockDim.x + threadIdx.x;
    int cast4 = N * 32;                      // N*128/4 vec4 groups
    if (i < cast4) {
        f32x4 v = *(const f32x4*)(inp + (size_t)i * 4);
        u16x4 o;
        #pragma unroll
        for (int j = 0; j < 4; j++) o[j] = f2bf(fin(v[j]));
        *(u16x4*)(Xb + (size_t)i * 4) = o;
        return;
    }
    i -= cast4;
    if (i < N) { deg[i] = 0; return; }
    i -= N;
    if (i >= 0 && i < 128 * 256) {          // W1 [128 x 256] -> Wt1 [256 x 128]
        int k = i >> 8, m = i & 255;
        Wt1[m * 128 + k] = f2bf(fin(W1[i]));
        return;
    }
    i -= 128 * 256;
    if (i >= 0 && i < 256 * 256) {
        int k = i >> 8, m = i & 255;
        Wt2[m * 256 + k] = f2bf(fin(W2[i]));
        return;
    }
    i -= 256 * 256;
    if (i >= 0 && i < 256 * 256) {
        int k = i >> 8, m = i & 255;
        Wt3[m * 256 + k] = f2bf(fin(W3[i]));
    }
}

// ---------------------------------------------------------------- CSR build
// count: one atomic per edge; the returned value IS the edge's rank within its
// destination row -> stored coalesced. This lets the placement pass run with
// ZERO atomics (scatter was a second full 850K-random-atomic pass before).
__global__ void count_kernel(const int* __restrict__ dst, int* __restrict__ deg,
                             int* __restrict__ rank, int E, int N) {
    int i = blockIdx.x * blockDim.x + threadIdx.x;
    if (i < E + N) {
        int d = (i < E) ? dst[i] : (i - E);   // self-loops appended
        d = ((unsigned)d < (unsigned)N) ? d : 0;
        rank[i] = atomicAdd(&deg[d], 1);
    }
}

// Single-dispatch scan: block b redundantly sums deg[0 .. b*1024), then scans
// its own 1024-element chunk (O(B^2) pre-sum is cheap at B=49).
__global__ __launch_bounds__(256) void scan_kernel(const int* __restrict__ deg,
                                                   int* __restrict__ rowstart, int N) {
    __shared__ int wsum[4];
    __shared__ int sm[256];
    int b = blockIdx.x, tid = threadIdx.x;
    int start = b * 1024;
    int pre = 0;
    for (int i = tid; i < start; i += 256) pre += deg[i];
    #pragma unroll
    for (int off = 1; off <= 32; off <<= 1) pre += __shfl_xor(pre, off);
    if ((tid & 63) == 0) wsum[tid >> 6] = pre;
    __syncthreads();
    int block_pre = wsum[0] + wsum[1] + wsum[2] + wsum[3];

    int base = start + tid * 4;
    int v[4]; int s = 0;
    #pragma unroll
    for (int j = 0; j < 4; j++) { int i = base + j; v[j] = (i < N) ? deg[i] : 0; s += v[j]; }
    sm[tid] = s;
    __syncthreads();
    for (int off = 1; off < 256; off <<= 1) {
        int t = (tid >= off) ? sm[tid - off] : 0;
        __syncthreads();
        sm[tid] += t;
        __syncthreads();
    }
    int run = block_pre + sm[tid] - s;
    #pragma unroll
    for (int j = 0; j < 4; j++) {
        int i = base + j;
        if (i < N) { rowstart[i] = run; run += v[j]; }
    }
    if (b == gridDim.x - 1 && tid == 255) rowstart[N] = block_pre + sm[255];
}

// Atomic-free placement: pos = rowstart[d] + rank[i]. rowstart is a 200 KB
// L2-resident table, so the scattered read is cheap; the only scattered
// write is the csr store itself (unavoidable).
__global__ void place_kernel(const int* __restrict__ src, const int* __restrict__ dst,
                             const int* __restrict__ rowstart, const int* __restrict__ rank,
                             int* __restrict__ csr, int E, int N) {
    int i = blockIdx.x * blockDim.x + threadIdx.x;
    if (i < E + N) {
        int s, d;
        if (i < E) { s = src[i]; d = dst[i]; }
        else       { s = i - E; d = i - E; }
        s = ((unsigned)s < (unsigned)N) ? s : 0;
        d = ((unsigned)d < (unsigned)N) ? d : 0;
        int pos = rowstart[d] + rank[i];
        if ((unsigned)pos < (unsigned)(E + N)) csr[pos] = s;
    }
}

// ---------------------------------------------------------------- GEMM + fused alphas
// Hb[N x 256] = Xb[N x K] @ W; plus as/ad[n][h] = sum_c Hb[n][h*64+c]*att_{src,dst}[h*64+c]
// computed from the accumulators before the bf16 store (saves a full Hb re-read).
__global__ __launch_bounds__(256) void gemm_kernel(
        const u16* __restrict__ X, const u16* __restrict__ Wt,
        u16* __restrict__ Hout, const float* __restrict__ att_src,
        const float* __restrict__ att_dst, float* __restrict__ as_out,
        float* __restrict__ ad_out, int N, int K) {
    int wv = threadIdx.x >> 6, lane = threadIdx.x & 63;
    int quad = lane >> 4, l16 = lane & 15;
    int m0 = (blockIdx.x * 2 + (wv & 1)) * 32;
    int n0 = (wv >> 1) * 128;

    f32x4 acc[2][8];
    #pragma unroll
    for (int r = 0; r < 2; r++)
        #pragma unroll
        for (int c = 0; c < 8; c++) acc[r][c] = (f32x4){0.f, 0.f, 0.f, 0.f};

    for (int k0 = 0; k0 < K; k0 += 32) {
        s16x8 a[2], b[8];
        #pragma unroll
        for (int r = 0; r < 2; r++) {
            int row = m0 + r * 16 + l16;
            row = row < N ? row : N - 1;
            a[r] = *(const s16x8*)(X + (size_t)row * K + k0 + quad * 8);
        }
        #pragma unroll
        for (int c = 0; c < 8; c++) {
            int n = n0 + c * 16 + l16;
            b[c] = *(const s16x8*)(Wt + (size_t)n * K + k0 + quad * 8);
        }
        #pragma unroll
        for (int r = 0; r < 2; r++)
            #pragma unroll
            for (int c = 0; c < 8; c++)
                acc[r][c] = __builtin_amdgcn_mfma_f32_16x16x32_bf16(a[r], b[c], acc[r][c], 0, 0, 0);
    }

    // Epilogue: store bf16 H and accumulate alpha partials.
    // C/D layout: col = n0 + c*16 + l16, row = m0 + r*16 + quad*4 + j.
    int head0 = n0 >> 6;
    float aps[2][4][2], apd[2][4][2];   // [r][j][hh]
    #pragma unroll
    for (int r = 0; r < 2; r++)
        #pragma unroll
        for (int j = 0; j < 4; j++)
            aps[r][j][0] = aps[r][j][1] = apd[r][j][0] = apd[r][j][1] = 0.f;

    #pragma unroll
    for (int r = 0; r < 2; r++) {
        int rowb = m0 + r * 16 + quad * 4;
        #pragma unroll
        for (int c = 0; c < 8; c++) {
            int col = n0 + c * 16 + l16;
            float av = fin(att_src[col]);
            float dv = fin(att_dst[col]);
            int hh = c >> 2;
            #pragma unroll
            for (int j = 0; j < 4; j++) {
                int row = rowb + j;
                float v = acc[r][c][j];
                aps[r][j][hh] += v * av;
                apd[r][j][hh] += v * dv;
                if (row < N) Hout[(size_t)row * 256 + col] = f2bf(v);
            }
        }
    }
    // reduce over the 16 l16 lanes (columns within a head-half)
    #pragma unroll
    for (int off = 1; off <= 8; off <<= 1) {
        #pragma unroll
        for (int r = 0; r < 2; r++)
            #pragma unroll
            for (int j = 0; j < 4; j++) {
                aps[r][j][0] += __shfl_xor(aps[r][j][0], off);
                aps[r][j][1] += __shfl_xor(aps[r][j][1], off);
                apd[r][j][0] += __shfl_xor(apd[r][j][0], off);
                apd[r][j][1] += __shfl_xor(apd[r][j][1], off);
            }
    }
    if (l16 == 0) {
        #pragma unroll
        for (int r = 0; r < 2; r++) {
            int rowb = m0 + r * 16 + quad * 4;
            #pragma unroll
            for (int j = 0; j < 4; j++) {
                int row = rowb + j;
                if (row < N) {
                    #pragma unroll
                    for (int hh = 0; hh < 2; hh++) {
                        as_out[row * 4 + head0 + hh] = aps[r][j][hh];
                        ad_out[row * 4 + head0 + hh] = apd[r][j][hh];
                    }
                }
            }
        }
    }
}

// ---------------------------------------------------------------- fused softmax-gather
// (R6 version — measured 68.7 us.) Wave per node; 2 half-wave edge slots; lane
// covers 8 channels (16 B load) of head h = (lane&31)>>3. Inline max-free softmax
// (clamp 80). Edge loop unrolled x2 per slot -> 4 independent row loads in flight.
__global__ __launch_bounds__(256) void gather_kernel(
        const u16* __restrict__ Hb, const float* __restrict__ asrc,
        const float* __restrict__ adst, const int* __restrict__ rowstart,
        const int* __restrict__ csr, const float* __restrict__ bias,
        u16* __restrict__ outb, float* __restrict__ outf, int write_f32,
        int N, int Etot) {
    int wv = threadIdx.x >> 6, lane = threadIdx.x & 63;
    int n = blockIdx.x * 4 + wv;
    if (n >= N) return;
    int es = lane >> 5, c = lane & 31;    // edge slot; 8-channel group
    int h = c >> 3;
    int i0 = rowstart[n], i1 = rowstart[n + 1];
    i0 = min(max(i0, 0), Etot);
    i1 = min(max(i1, i0), Etot);

    float adh = adst[n * 4 + h];
    float acc[8];
    float ws = 0.f;
    #pragma unroll
    for (int j = 0; j < 8; j++) acc[j] = 0.f;

    int i = i0 + es;
    for (; i + 2 < i1; i += 4) {
        int sA = csr[i], sB = csr[i + 2];
        sA = ((unsigned)sA < (unsigned)N) ? sA : 0;
        sB = ((unsigned)sB < (unsigned)N) ? sB : 0;
        float eA = asrc[sA * 4 + h] + adh;
        float eB = asrc[sB * 4 + h] + adh;
        s16x8 hvA = *(const s16x8*)(Hb + (size_t)sA * 256 + c * 8);
        s16x8 hvB = *(const s16x8*)(Hb + (size_t)sB * 256 + c * 8);
        eA = eA > 0.f ? eA : SLOPE * eA;
        eB = eB > 0.f ? eB : SLOPE * eB;
        float wA = __expf(fminf(eA, 80.f));
        float wB = __expf(fminf(eB, 80.f));
        ws += wA + wB;
        #pragma unroll
        for (int j = 0; j < 8; j++)
            acc[j] += wA * bf2f((u16)hvA[j]) + wB * bf2f((u16)hvB[j]);
    }
    if (i < i1) {
        int s = csr[i];
        s = ((unsigned)s < (unsigned)N) ? s : 0;
        float e = asrc[s * 4 + h] + adh;
        s16x8 hv = *(const s16x8*)(Hb + (size_t)s * 256 + c * 8);
        e = e > 0.f ? e : SLOPE * e;
        float w = __expf(fminf(e, 80.f));
        ws += w;
        #pragma unroll
        for (int j = 0; j < 8; j++) acc[j] += w * bf2f((u16)hv[j]);
    }

    ws += __shfl_xor(ws, 32);
    #pragma unroll
    for (int j = 0; j < 8; j++) acc[j] += __shfl_xor(acc[j], 32);

    if (es == 0) {
        float invh = (ws > 0.f) ? 1.f / ws : 0.f;
        f32x4 blo = *(const f32x4*)(bias + c * 8);
        f32x4 bhi = *(const f32x4*)(bias + c * 8 + 4);
        size_t base = (size_t)n * 256 + c * 8;
        float o[8];
        #pragma unroll
        for (int j = 0; j < 8; j++) {
            float v = acc[j] * invh + fin(j < 4 ? blo[j] : bhi[j - 4]);
            o[j] = v > 0.f ? v : (__expf(v) - 1.f);   // ELU
        }
        if (write_f32) {
            f32x4 lo = {o[0], o[1], o[2], o[3]}, hi = {o[4], o[5], o[6], o[7]};
            *(f32x4*)(outf + base) = lo;
            *(f32x4*)(outf + base + 4) = hi;
        } else {
            s16x8 ob;
            #pragma unroll
            for (int j = 0; j < 8; j++) ob[j] = (short)f2bf(o[j]);
            *(s16x8*)(outb + base) = ob;
        }
    }
}

// ---------------------------------------------------------------- launch
extern "C" void kernel_launch(void* const* d_in, const int* in_sizes, int n_in,
                              void* d_out, int out_size, void* d_ws, size_t ws_size,
                              hipStream_t stream) {
    const float* inp  = (const float*)d_in[0];
    const int*   ei   = (const int*)d_in[1];
    const float* W1   = (const float*)d_in[2];
    const float* at_s1= (const float*)d_in[3];
    const float* at_d1= (const float*)d_in[4];
    const float* b1   = (const float*)d_in[5];
    const float* W2   = (const float*)d_in[6];
    const float* at_s2= (const float*)d_in[7];
    const float* at_d2= (const float*)d_in[8];
    const float* b2   = (const float*)d_in[9];
    const float* W3   = (const float*)d_in[10];
    const float* at_s3= (const float*)d_in[11];
    const float* at_d3= (const float*)d_in[12];
    const float* b3   = (const float*)d_in[13];

    const int N = in_sizes[0] / 128;   // 50000
    const int E = in_sizes[1] / 2;     // 800000
    const int Etot = E + N;
    const int* esrc = ei;
    const int* edst = ei + E;

    char* p = (char*)d_ws;
    auto alloc = [&](size_t b) -> void* {
        void* q = (void*)p;
        p += (b + 255) & ~(size_t)255;
        return q;
    };
    u16*   Xb       = (u16*)alloc((size_t)N * 256 * 2);
    u16*   Hb       = (u16*)alloc((size_t)N * 256 * 2);
    u16*   Wt1      = (u16*)alloc((size_t)128 * 256 * 2);
    u16*   Wt2      = (u16*)alloc((size_t)256 * 256 * 2);
    u16*   Wt3      = (u16*)alloc((size_t)256 * 256 * 2);
    float* asb      = (float*)alloc((size_t)N * 4 * 4);
    float* adb      = (float*)alloc((size_t)N * 4 * 4);
    int*   deg      = (int*)alloc((size_t)N * 4);
    int*   rowstart = (int*)alloc((size_t)(N + 1) * 4);
    int*   rank     = (int*)alloc((size_t)Etot * 4);
    int*   csr      = (int*)alloc((size_t)Etot * 4);
    float* outf     = (float*)d_out;

    const int SB = (N + 1023) / 1024;
    const int prep_total = N * 32 + N + 128 * 256 + 2 * 256 * 256;

    prep_kernel<<<(prep_total + 255) / 256, 256, 0, stream>>>(
        inp, Xb, W1, Wt1, W2, Wt2, W3, Wt3, deg, N);
    count_kernel<<<(Etot + 255) / 256, 256, 0, stream>>>(edst, deg, rank, E, N);
    scan_kernel<<<SB, 256, 0, stream>>>(deg, rowstart, N);
    place_kernel<<<(Etot + 255) / 256, 256, 0, stream>>>(esrc, edst, rowstart, rank, csr, E, N);

    const int gemm_grid = (N + 63) / 64;
    const int node_grid = (N + 3) / 4;

    // layer 1 (K=128)
    gemm_kernel<<<gemm_grid, 256, 0, stream>>>(Xb, Wt1, Hb, at_s1, at_d1, asb, adb, N, 128);
    gather_kernel<<<node_grid, 256, 0, stream>>>(Hb, asb, adb, rowstart, csr, b1,
                                                 Xb, outf, 0, N, Etot);
    // layer 2 (K=256)
    gemm_kernel<<<gemm_grid, 256, 0, stream>>>(Xb, Wt2, Hb, at_s2, at_d2, asb, adb, N, 256);
    gather_kernel<<<node_grid, 256, 0, stream>>>(Hb, asb, adb, rowstart, csr, b2,
                                                 Xb, outf, 0, N, Etot);
    // layer 3 (K=256) -> fp32 d_out
    gemm_kernel<<<gemm_grid, 256, 0, stream>>>(Xb, Wt3, Hb, at_s3, at_d3, asb, adb, N, 256);
    gather_kernel<<<node_grid, 256, 0, stream>>>(Hb, asb, adb, rowstart, csr, b3,
                                                 Xb, outf, 1, N, Etot);
}

// Round 3
// 444.381 us; speedup vs baseline: 1.7334x; 1.1233x over previous
//
#include <hip/hip_runtime.h>
#include <hip/hip_bf16.h>
#include <stdint.h>

#define HEADS 4
#define SLOPE 0.2f

typedef unsigned short u16;
typedef float f32x4 __attribute__((ext_vector_type(4)));
typedef short s16x8 __attribute__((ext_vector_type(8)));
typedef unsigned short u16x4 __attribute__((ext_vector_type(4)));

__device__ __forceinline__ u16 f2bf(float f) {
    unsigned int u = __float_as_uint(f);
    u = (u + 0x7fffu + ((u >> 16) & 1u)) >> 16;   // round-to-nearest-even
    return (u16)u;
}
__device__ __forceinline__ float bf2f(u16 v) {
    return __uint_as_float(((unsigned int)v) << 16);
}
__device__ __forceinline__ float fin(float x) {
    return (x == x && fabsf(x) < 1e30f) ? x : 0.f;
}

// ---------------------------------------------------------------- fused prep
// Vectorized cast inp -> Xb (f32x4 -> u16x4), zero(deg), transpose W1/W2/W3.
__global__ void prep_kernel(const float* __restrict__ inp, u16* __restrict__ Xb,
                            const float* __restrict__ W1, u16* __restrict__ Wt1,
                            const float* __restrict__ W2, u16* __restrict__ Wt2,
                            const float* __restrict__ W3, u16* __restrict__ Wt3,
                            int* __restrict__ deg, int N) {
    int i = blockIdx.x * blockDim.x + threadIdx.x;
    int cast4 = N * 32;                      // N*128/4 vec4 groups
    if (i < cast4) {
        f32x4 v = *(const f32x4*)(inp + (size_t)i * 4);
        u16x4 o;
        #pragma unroll
        for (int j = 0; j < 4; j++) o[j] = f2bf(fin(v[j]));
        *(u16x4*)(Xb + (size_t)i * 4) = o;
        return;
    }
    i -= cast4;
    if (i < N) { deg[i] = 0; return; }
    i -= N;
    if (i >= 0 && i < 128 * 256) {          // W1 [128 x 256] -> Wt1 [256 x 128]
        int k = i >> 8, m = i & 255;
        Wt1[m * 128 + k] = f2bf(fin(W1[i]));
        return;
    }
    i -= 128 * 256;
    if (i >= 0 && i < 256 * 256) {
        int k = i >> 8, m = i & 255;
        Wt2[m * 256 + k] = f2bf(fin(W2[i]));
        return;
    }
    i -= 256 * 256;
    if (i >= 0 && i < 256 * 256) {
        int k = i >> 8, m = i & 255;
        Wt3[m * 256 + k] = f2bf(fin(W3[i]));
    }
}

// ---------------------------------------------------------------- CSR build
// count: one atomic per edge; the returned value IS the edge's rank within its
// destination row -> stored coalesced, so placement runs with zero atomics.
__global__ void count_kernel(const int* __restrict__ dst, int* __restrict__ deg,
                             int* __restrict__ rank, int E, int N) {
    int i = blockIdx.x * blockDim.x + threadIdx.x;
    if (i < E + N) {
        int d = (i < E) ? dst[i] : (i - E);   // self-loops appended
        d = ((unsigned)d < (unsigned)N) ? d : 0;
        rank[i] = atomicAdd(&deg[d], 1);
    }
}

// Single-dispatch scan: block b redundantly sums deg[0 .. b*1024), then scans
// its own 1024-element chunk (O(B^2) pre-sum is cheap at B=49).
__global__ __launch_bounds__(256) void scan_kernel(const int* __restrict__ deg,
                                                   int* __restrict__ rowstart, int N) {
    __shared__ int wsum[4];
    __shared__ int sm[256];
    int b = blockIdx.x, tid = threadIdx.x;
    int start = b * 1024;
    int pre = 0;
    for (int i = tid; i < start; i += 256) pre += deg[i];
    #pragma unroll
    for (int off = 1; off <= 32; off <<= 1) pre += __shfl_xor(pre, off);
    if ((tid & 63) == 0) wsum[tid >> 6] = pre;
    __syncthreads();
    int block_pre = wsum[0] + wsum[1] + wsum[2] + wsum[3];

    int base = start + tid * 4;
    int v[4]; int s = 0;
    #pragma unroll
    for (int j = 0; j < 4; j++) { int i = base + j; v[j] = (i < N) ? deg[i] : 0; s += v[j]; }
    sm[tid] = s;
    __syncthreads();
    for (int off = 1; off < 256; off <<= 1) {
        int t = (tid >= off) ? sm[tid - off] : 0;
        __syncthreads();
        sm[tid] += t;
        __syncthreads();
    }
    int run = block_pre + sm[tid] - s;
    #pragma unroll
    for (int j = 0; j < 4; j++) {
        int i = base + j;
        if (i < N) { rowstart[i] = run; run += v[j]; }
    }
    if (b == gridDim.x - 1 && tid == 255) rowstart[N] = block_pre + sm[255];
}

// Atomic-free placement: pos = rowstart[d] + rank[i].
__global__ void place_kernel(const int* __restrict__ src, const int* __restrict__ dst,
                             const int* __restrict__ rowstart, const int* __restrict__ rank,
                             int* __restrict__ csr, int E, int N) {
    int i = blockIdx.x * blockDim.x + threadIdx.x;
    if (i < E + N) {
        int s, d;
        if (i < E) { s = src[i]; d = dst[i]; }
        else       { s = i - E; d = i - E; }
        s = ((unsigned)s < (unsigned)N) ? s : 0;
        d = ((unsigned)d < (unsigned)N) ? d : 0;
        int pos = rowstart[d] + rank[i];
        if ((unsigned)pos < (unsigned)(E + N)) csr[pos] = s;
    }
}

// ---------------------------------------------------------------- GEMM + fused alphas
// LDS-staged MFMA GEMM. Block tile 64 x 256 (full N), BK=64, 4 waves; each wave
// owns a 64x64 column strip = exactly one head. LDS rows padded to 72 elems
// (144 B) so ds_read_b128 fragments land 2-way bank aliasing (free). Staging
// loads are coalesced 128-B row segments; next k-step's loads issue before the
// MFMA block so HBM latency hides under compute. MFMA k-order identical to the
// previous direct-load version -> bitwise-same accumulators.
__global__ __launch_bounds__(256, 3) void gemm_kernel(
        const u16* __restrict__ X, const u16* __restrict__ Wt,
        u16* __restrict__ Hout, const float* __restrict__ att_src,
        const float* __restrict__ att_dst, float* __restrict__ as_out,
        float* __restrict__ ad_out, int N, int K) {
    __shared__ __align__(16) u16 As[64 * 72];    //  9216 B
    __shared__ __align__(16) u16 Bs[256 * 72];   // 36864 B
    int t = threadIdx.x;
    int wv = t >> 6, lane = t & 63;
    int quad = lane >> 4, l16 = lane & 15;
    int m0 = blockIdx.x * 64;
    int n0 = wv * 64;
    int srow = t >> 3, sslot = t & 7;   // staging: row-within-lot, 16B slot

    f32x4 acc[4][4];
    #pragma unroll
    for (int r = 0; r < 4; r++)
        #pragma unroll
        for (int c = 0; c < 4; c++) acc[r][c] = (f32x4){0.f, 0.f, 0.f, 0.f};

    const int nsteps = K >> 6;
    s16x8 ra[2], rb[8];
    {   // prologue: load k-step 0 to regs
        #pragma unroll
        for (int s = 0; s < 2; s++) {
            int rg = m0 + s * 32 + srow; rg = rg < N ? rg : N - 1;
            ra[s] = *(const s16x8*)(X + (size_t)rg * K + sslot * 8);
        }
        #pragma unroll
        for (int s = 0; s < 8; s++) {
            int n = s * 32 + srow;
            rb[s] = *(const s16x8*)(Wt + (size_t)n * K + sslot * 8);
        }
    }
    for (int step = 0; step < nsteps; step++) {
        __syncthreads();
        #pragma unroll
        for (int s = 0; s < 2; s++)
            *(s16x8*)(As + (s * 32 + srow) * 72 + sslot * 8) = ra[s];
        #pragma unroll
        for (int s = 0; s < 8; s++)
            *(s16x8*)(Bs + (s * 32 + srow) * 72 + sslot * 8) = rb[s];
        __syncthreads();
        if (step + 1 < nsteps) {        // prefetch next k-step (overlaps MFMA)
            int k0 = (step + 1) << 6;
            #pragma unroll
            for (int s = 0; s < 2; s++) {
                int rg = m0 + s * 32 + srow; rg = rg < N ? rg : N - 1;
                ra[s] = *(const s16x8*)(X + (size_t)rg * K + k0 + sslot * 8);
            }
            #pragma unroll
            for (int s = 0; s < 8; s++) {
                int n = s * 32 + srow;
                rb[s] = *(const s16x8*)(Wt + (size_t)n * K + k0 + sslot * 8);
            }
        }
        #pragma unroll
        for (int subk = 0; subk < 2; subk++) {
            s16x8 af[4], bf[4];
            #pragma unroll
            for (int r = 0; r < 4; r++)
                af[r] = *(const s16x8*)(As + (r * 16 + l16) * 72 + subk * 32 + quad * 8);
            #pragma unroll
            for (int c = 0; c < 4; c++)
                bf[c] = *(const s16x8*)(Bs + (n0 + c * 16 + l16) * 72 + subk * 32 + quad * 8);
            #pragma unroll
            for (int r = 0; r < 4; r++)
                #pragma unroll
                for (int c = 0; c < 4; c++)
                    acc[r][c] = __builtin_amdgcn_mfma_f32_16x16x32_bf16(af[r], bf[c], acc[r][c], 0, 0, 0);
        }
    }

    // Epilogue: store bf16 H and alpha partials. C/D layout:
    // col = n0 + c*16 + l16, row = m0 + r*16 + quad*4 + j. Wave = head wv.
    float aps[4][4], apd[4][4];   // [r][j]
    #pragma unroll
    for (int r = 0; r < 4; r++)
        #pragma unroll
        for (int j = 0; j < 4; j++) { aps[r][j] = 0.f; apd[r][j] = 0.f; }

    #pragma unroll
    for (int r = 0; r < 4; r++) {
        int rowb = m0 + r * 16 + quad * 4;
        #pragma unroll
        for (int c = 0; c < 4; c++) {
            int col = n0 + c * 16 + l16;
            float av = fin(att_src[col]);
            float dv = fin(att_dst[col]);
            #pragma unroll
            for (int j = 0; j < 4; j++) {
                int row = rowb + j;
                float v = acc[r][c][j];
                aps[r][j] += v * av;
                apd[r][j] += v * dv;
                if (row < N) Hout[(size_t)row * 256 + col] = f2bf(v);
            }
        }
    }
    #pragma unroll
    for (int off = 1; off <= 8; off <<= 1)
        #pragma unroll
        for (int r = 0; r < 4; r++)
            #pragma unroll
            for (int j = 0; j < 4; j++) {
                aps[r][j] += __shfl_xor(aps[r][j], off);
                apd[r][j] += __shfl_xor(apd[r][j], off);
            }
    if (l16 == 0) {
        #pragma unroll
        for (int r = 0; r < 4; r++) {
            int rowb = m0 + r * 16 + quad * 4;
            #pragma unroll
            for (int j = 0; j < 4; j++) {
                int row = rowb + j;
                if (row < N) {
                    as_out[row * 4 + wv] = aps[r][j];
                    ad_out[row * 4 + wv] = apd[r][j];
                }
            }
        }
    }
}

// ---------------------------------------------------------------- fused softmax-gather
// Wave per node; 2 half-wave edge slots; lane covers 8 channels (16 B load) of
// head h = (lane&31)>>3. Inline max-free softmax (clamp 80). Edge loop unrolled
// x4 per slot -> 8 independent row loads in flight per wave (ILP bump).
__global__ __launch_bounds__(256) void gather_kernel(
        const u16* __restrict__ Hb, const float* __restrict__ asrc,
        const float* __restrict__ adst, const int* __restrict__ rowstart,
        const int* __restrict__ csr, const float* __restrict__ bias,
        u16* __restrict__ outb, float* __restrict__ outf, int write_f32,
        int N, int Etot) {
    int wv = threadIdx.x >> 6, lane = threadIdx.x & 63;
    int n = blockIdx.x * 4 + wv;
    if (n >= N) return;
    int es = lane >> 5, c = lane & 31;    // edge slot; 8-channel group
    int h = c >> 3;
    int i0 = rowstart[n], i1 = rowstart[n + 1];
    i0 = min(max(i0, 0), Etot);
    i1 = min(max(i1, i0), Etot);

    float adh = adst[n * 4 + h];
    float acc[8];
    float ws = 0.f;
    #pragma unroll
    for (int j = 0; j < 8; j++) acc[j] = 0.f;

    int i = i0 + es;
    for (; i + 6 < i1; i += 8) {          // x4 unroll: 4 independent lines/slot
        int ss[4];
        #pragma unroll
        for (int u = 0; u < 4; u++) {
            int s = csr[i + 2 * u];
            ss[u] = ((unsigned)s < (unsigned)N) ? s : 0;
        }
        float e[4]; s16x8 hv[4];
        #pragma unroll
        for (int u = 0; u < 4; u++) {
            e[u] = asrc[ss[u] * 4 + h] + adh;
            hv[u] = *(const s16x8*)(Hb + (size_t)ss[u] * 256 + c * 8);
        }
        #pragma unroll
        for (int u = 0; u < 4; u++) {
            float ee = e[u] > 0.f ? e[u] : SLOPE * e[u];
            float w = __expf(fminf(ee, 80.f));
            ws += w;
            #pragma unroll
            for (int j = 0; j < 8; j++) acc[j] += w * bf2f((u16)hv[u][j]);
        }
    }
    for (; i + 2 < i1; i += 4) {
        int sA = csr[i], sB = csr[i + 2];
        sA = ((unsigned)sA < (unsigned)N) ? sA : 0;
        sB = ((unsigned)sB < (unsigned)N) ? sB : 0;
        float eA = asrc[sA * 4 + h] + adh;
        float eB = asrc[sB * 4 + h] + adh;
        s16x8 hvA = *(const s16x8*)(Hb + (size_t)sA * 256 + c * 8);
        s16x8 hvB = *(const s16x8*)(Hb + (size_t)sB * 256 + c * 8);
        eA = eA > 0.f ? eA : SLOPE * eA;
        eB = eB > 0.f ? eB : SLOPE * eB;
        float wA = __expf(fminf(eA, 80.f));
        float wB = __expf(fminf(eB, 80.f));
        ws += wA + wB;
        #pragma unroll
        for (int j = 0; j < 8; j++)
            acc[j] += wA * bf2f((u16)hvA[j]) + wB * bf2f((u16)hvB[j]);
    }
    if (i < i1) {
        int s = csr[i];
        s = ((unsigned)s < (unsigned)N) ? s : 0;
        float e = asrc[s * 4 + h] + adh;
        s16x8 hv = *(const s16x8*)(Hb + (size_t)s * 256 + c * 8);
        e = e > 0.f ? e : SLOPE * e;
        float w = __expf(fminf(e, 80.f));
        ws += w;
        #pragma unroll
        for (int j = 0; j < 8; j++) acc[j] += w * bf2f((u16)hv[j]);
    }

    ws += __shfl_xor(ws, 32);
    #pragma unroll
    for (int j = 0; j < 8; j++) acc[j] += __shfl_xor(acc[j], 32);

    if (es == 0) {
        float invh = (ws > 0.f) ? 1.f / ws : 0.f;
        f32x4 blo = *(const f32x4*)(bias + c * 8);
        f32x4 bhi = *(const f32x4*)(bias + c * 8 + 4);
        size_t base = (size_t)n * 256 + c * 8;
        float o[8];
        #pragma unroll
        for (int j = 0; j < 8; j++) {
            float v = acc[j] * invh + fin(j < 4 ? blo[j] : bhi[j - 4]);
            o[j] = v > 0.f ? v : (__expf(v) - 1.f);   // ELU
        }
        if (write_f32) {
            f32x4 lo = {o[0], o[1], o[2], o[3]}, hi = {o[4], o[5], o[6], o[7]};
            *(f32x4*)(outf + base) = lo;
            *(f32x4*)(outf + base + 4) = hi;
        } else {
            s16x8 ob;
            #pragma unroll
            for (int j = 0; j < 8; j++) ob[j] = (short)f2bf(o[j]);
            *(s16x8*)(outb + base) = ob;
        }
    }
}

// ---------------------------------------------------------------- launch
extern "C" void kernel_launch(void* const* d_in, const int* in_sizes, int n_in,
                              void* d_out, int out_size, void* d_ws, size_t ws_size,
                              hipStream_t stream) {
    const float* inp  = (const float*)d_in[0];
    const int*   ei   = (const int*)d_in[1];
    const float* W1   = (const float*)d_in[2];
    const float* at_s1= (const float*)d_in[3];
    const float* at_d1= (const float*)d_in[4];
    const float* b1   = (const float*)d_in[5];
    const float* W2   = (const float*)d_in[6];
    const float* at_s2= (const float*)d_in[7];
    const float* at_d2= (const float*)d_in[8];
    const float* b2   = (const float*)d_in[9];
    const float* W3   = (const float*)d_in[10];
    const float* at_s3= (const float*)d_in[11];
    const float* at_d3= (const float*)d_in[12];
    const float* b3   = (const float*)d_in[13];

    const int N = in_sizes[0] / 128;   // 50000
    const int E = in_sizes[1] / 2;     // 800000
    const int Etot = E + N;
    const int* esrc = ei;
    const int* edst = ei + E;

    char* p = (char*)d_ws;
    auto alloc = [&](size_t b) -> void* {
        void* q = (void*)p;
        p += (b + 255) & ~(size_t)255;
        return q;
    };
    u16*   Xb       = (u16*)alloc((size_t)N * 256 * 2);
    u16*   Hb       = (u16*)alloc((size_t)N * 256 * 2);
    u16*   Wt1      = (u16*)alloc((size_t)128 * 256 * 2);
    u16*   Wt2      = (u16*)alloc((size_t)256 * 256 * 2);
    u16*   Wt3      = (u16*)alloc((size_t)256 * 256 * 2);
    float* asb      = (float*)alloc((size_t)N * 4 * 4);
    float* adb      = (float*)alloc((size_t)N * 4 * 4);
    int*   deg      = (int*)alloc((size_t)N * 4);
    int*   rowstart = (int*)alloc((size_t)(N + 1) * 4);
    int*   rank     = (int*)alloc((size_t)Etot * 4);
    int*   csr      = (int*)alloc((size_t)Etot * 4);
    float* outf     = (float*)d_out;

    const int SB = (N + 1023) / 1024;
    const int prep_total = N * 32 + N + 128 * 256 + 2 * 256 * 256;

    prep_kernel<<<(prep_total + 255) / 256, 256, 0, stream>>>(
        inp, Xb, W1, Wt1, W2, Wt2, W3, Wt3, deg, N);
    count_kernel<<<(Etot + 255) / 256, 256, 0, stream>>>(edst, deg, rank, E, N);
    scan_kernel<<<SB, 256, 0, stream>>>(deg, rowstart, N);
    place_kernel<<<(Etot + 255) / 256, 256, 0, stream>>>(esrc, edst, rowstart, rank, csr, E, N);

    const int gemm_grid = (N + 63) / 64;
    const int node_grid = (N + 3) / 4;

    // layer 1 (K=128)
    gemm_kernel<<<gemm_grid, 256, 0, stream>>>(Xb, Wt1, Hb, at_s1, at_d1, asb, adb, N, 128);
    gather_kernel<<<node_grid, 256, 0, stream>>>(Hb, asb, adb, rowstart, csr, b1,
                                                 Xb, outf, 0, N, Etot);
    // layer 2 (K=256)
    gemm_kernel<<<gemm_grid, 256, 0, stream>>>(Xb, Wt2, Hb, at_s2, at_d2, asb, adb, N, 256);
    gather_kernel<<<node_grid, 256, 0, stream>>>(Hb, asb, adb, rowstart, csr, b2,
                                                 Xb, outf, 0, N, Etot);
    // layer 3 (K=256) -> fp32 d_out
    gemm_kernel<<<gemm_grid, 256, 0, stream>>>(Xb, Wt3, Hb, at_s3, at_d3, asb, adb, N, 256);
    gather_kernel<<<node_grid, 256, 0, stream>>>(Hb, asb, adb, rowstart, csr, b3,
                                                 Xb, outf, 1, N, Etot);
}